// Round 1
// baseline (3349.084 us; speedup 1.0000x reference)
//
#include <hip/hip_runtime.h>
#include <math.h>

#define NN 100000
#define KEXP 4
#define EE 1600000
#define F_IN 256
#define F_MID 64
#define F_OUT 2
#define EPSV 1e-5f

// ---------------- degree histogram ----------------
__global__ __launch_bounds__(256) void deg_kernel(const int* __restrict__ dst,
                                                  int* __restrict__ cnt, int E) {
    int tid = blockIdx.x * blockDim.x + threadIdx.x;
    if (tid < E) atomicAdd(&cnt[dst[tid]], 1);
}

__global__ __launch_bounds__(256) void dis_kernel(const int* __restrict__ cnt,
                                                  float* __restrict__ dis, int n) {
    int i = blockIdx.x * blockDim.x + threadIdx.x;
    if (i < n) dis[i] = rsqrtf((float)cnt[i] + 2.0f);
}

// ---------------- GEMM1: h = A @ W (M x 256 x 64), epilogue writes h and
// agg_init = 2*dis^2*h + b1 ----------------
__global__ __launch_bounds__(256) void gemm1_kernel(
    const float* __restrict__ A,    // [M,256]
    const float* __restrict__ W,    // [256,64]
    const float* __restrict__ b1,   // [64]
    const float* __restrict__ dis,  // [M]
    float* __restrict__ h,          // [M,64]
    float* __restrict__ agg,        // [M,64]
    int M) {
    __shared__ __align__(16) float As[64][65];
    __shared__ __align__(16) float Ws[64][68];
    int t = threadIdx.x;
    int row0 = blockIdx.x * 64;
    int tr = t >> 4;   // 0..15
    int tc = t & 15;   // 0..15
    float acc[4][4] = {{0.f}};

    for (int kc = 0; kc < 256; kc += 64) {
        // load A tile 64x64 (1024 float4s, 4 per thread)
        for (int i = 0; i < 4; i++) {
            int fid = t + i * 256;
            int r = fid >> 4;
            int c4 = (fid & 15) << 2;
            int row = row0 + r;
            float4 v = make_float4(0.f, 0.f, 0.f, 0.f);
            if (row < M) v = *(const float4*)&A[(size_t)row * 256 + kc + c4];
            As[r][c4] = v.x; As[r][c4 + 1] = v.y; As[r][c4 + 2] = v.z; As[r][c4 + 3] = v.w;
        }
        // load W tile 64x64
        for (int i = 0; i < 4; i++) {
            int fid = t + i * 256;
            int r = fid >> 4;
            int c4 = (fid & 15) << 2;
            float4 v = *(const float4*)&W[(size_t)(kc + r) * 64 + c4];
            *(float4*)&Ws[r][c4] = v;
        }
        __syncthreads();
        for (int kk = 0; kk < 64; kk++) {
            float a0 = As[tr * 4 + 0][kk];
            float a1 = As[tr * 4 + 1][kk];
            float a2 = As[tr * 4 + 2][kk];
            float a3 = As[tr * 4 + 3][kk];
            float4 w = *(const float4*)&Ws[kk][tc * 4];
            acc[0][0] += a0 * w.x; acc[0][1] += a0 * w.y; acc[0][2] += a0 * w.z; acc[0][3] += a0 * w.w;
            acc[1][0] += a1 * w.x; acc[1][1] += a1 * w.y; acc[1][2] += a1 * w.z; acc[1][3] += a1 * w.w;
            acc[2][0] += a2 * w.x; acc[2][1] += a2 * w.y; acc[2][2] += a2 * w.z; acc[2][3] += a2 * w.w;
            acc[3][0] += a3 * w.x; acc[3][1] += a3 * w.y; acc[3][2] += a3 * w.z; acc[3][3] += a3 * w.w;
        }
        __syncthreads();
    }
    float4 bb = *(const float4*)&b1[tc * 4];
    for (int i = 0; i < 4; i++) {
        int row = row0 + tr * 4 + i;
        if (row >= M) continue;
        float ds = dis[row];
        float sc = 2.f * ds * ds;
        float4 v = make_float4(acc[i][0], acc[i][1], acc[i][2], acc[i][3]);
        *(float4*)&h[(size_t)row * 64 + tc * 4] = v;
        float4 g;
        g.x = sc * v.x + bb.x; g.y = sc * v.y + bb.y;
        g.z = sc * v.z + bb.z; g.w = sc * v.w + bb.w;
        *(float4*)&agg[(size_t)row * 64 + tc * 4] = g;
    }
}

// ---------------- edge aggregation 1: one wave per edge, lane = feature ----
__global__ __launch_bounds__(256) void edge_agg1(const int* __restrict__ src,
                                                 const int* __restrict__ dst,
                                                 const float* __restrict__ dis,
                                                 const float* __restrict__ h,
                                                 float* agg, int E) {
    int wid = (int)((blockIdx.x * (size_t)blockDim.x + threadIdx.x) >> 6);
    int lane = threadIdx.x & 63;
    if (wid >= E) return;
    int s = src[wid], d = dst[wid];
    float coef = dis[s] * dis[d];
    unsafeAtomicAdd(&agg[(size_t)d * 64 + lane], h[(size_t)s * 64 + lane] * coef);
}

// ---------------- relu (in place) + per-block column sums ----------------
__global__ __launch_bounds__(256) void relu_stats(float* x, float* __restrict__ partial, int M) {
    int b = blockIdx.x;
    int t = threadIdx.x;
    int c = t & 63, w = t >> 6;
    float s = 0.f, sq = 0.f;
    for (int r = w; r < 256; r += 4) {
        int row = b * 256 + r;
        if (row < M) {
            float v = x[(size_t)row * 64 + c];
            v = fmaxf(v, 0.f);
            x[(size_t)row * 64 + c] = v;
            s += v; sq += v * v;
        }
    }
    __shared__ float ls[4][64];
    __shared__ float lq[4][64];
    ls[w][c] = s; lq[w][c] = sq;
    __syncthreads();
    if (t < 64) {
        float S = ls[0][t] + ls[1][t] + ls[2][t] + ls[3][t];
        float Q = lq[0][t] + lq[1][t] + lq[2][t] + lq[3][t];
        partial[(size_t)b * 128 + t] = S;
        partial[(size_t)b * 128 + 64 + t] = Q;
    }
}

__global__ void stats_fin(const float* __restrict__ partial, int nblk,
                          float* __restrict__ mu_istd, int M) {
    int c = threadIdx.x;  // 64 threads
    float S = 0.f, Q = 0.f;
    for (int b = 0; b < nblk; b++) {
        S += partial[(size_t)b * 128 + c];
        Q += partial[(size_t)b * 128 + 64 + c];
    }
    float mu = S / (float)M;
    float var = Q / (float)M - mu * mu;
    mu_istd[c] = mu;
    mu_istd[64 + c] = rsqrtf(var + EPSV);
}

// ---------------- BN apply + GEMM2 (64 -> 2) + agg2 init ----------------
__global__ __launch_bounds__(256) void bn_gemm2(const float* __restrict__ x,
                                                const float* __restrict__ mu_istd,
                                                const float* __restrict__ g,
                                                const float* __restrict__ bt,
                                                const float* __restrict__ W2,
                                                const float* __restrict__ b2,
                                                const float* __restrict__ dis,
                                                float* __restrict__ h2,
                                                float* __restrict__ agg2, int M) {
    int wid = (int)((blockIdx.x * (size_t)blockDim.x + threadIdx.x) >> 6);
    int c = threadIdx.x & 63;
    if (wid >= M) return;
    float v = x[(size_t)wid * 64 + c];
    v = (v - mu_istd[c]) * mu_istd[64 + c] * g[c] + bt[c];
    float p0 = v * W2[c * 2];
    float p1 = v * W2[c * 2 + 1];
    for (int off = 32; off; off >>= 1) {
        p0 += __shfl_down(p0, off);
        p1 += __shfl_down(p1, off);
    }
    if (c == 0) {
        float ds = dis[wid];
        float sc = 2.f * ds * ds;
        h2[(size_t)wid * 2] = p0;
        h2[(size_t)wid * 2 + 1] = p1;
        agg2[(size_t)wid * 2] = sc * p0 + b2[0];
        agg2[(size_t)wid * 2 + 1] = sc * p1 + b2[1];
    }
}

// ---------------- edge aggregation 2: one thread per edge ----------------
__global__ __launch_bounds__(256) void edge_agg2(const int* __restrict__ src,
                                                 const int* __restrict__ dst,
                                                 const float* __restrict__ dis,
                                                 const float* __restrict__ h2,
                                                 float* agg2, int E) {
    int e = blockIdx.x * blockDim.x + threadIdx.x;
    if (e >= E) return;
    int s = src[e], d = dst[e];
    float coef = dis[s] * dis[d];
    unsafeAtomicAdd(&agg2[(size_t)d * 2], h2[(size_t)s * 2] * coef);
    unsafeAtomicAdd(&agg2[(size_t)d * 2 + 1], h2[(size_t)s * 2 + 1] * coef);
}

// ---------------- gating + mixture output ----------------
__global__ __launch_bounds__(256) void final_kernel(const float* __restrict__ moe,
                                                    const float* __restrict__ Wg,
                                                    const float* __restrict__ bg,
                                                    const float* __restrict__ agg2,  // [K][N][2]
                                                    float* __restrict__ out, int M) {
    int n = (int)((blockIdx.x * (size_t)blockDim.x + threadIdx.x) >> 6);
    int lane = threadIdx.x & 63;
    if (n >= M) return;
    float4 mf = *(const float4*)&moe[(size_t)n * 256 + lane * 4];
    const float* wr = &Wg[lane * 16];
    float a0 = mf.x * wr[0] + mf.y * wr[4] + mf.z * wr[8] + mf.w * wr[12];
    float a1 = mf.x * wr[1] + mf.y * wr[5] + mf.z * wr[9] + mf.w * wr[13];
    float a2 = mf.x * wr[2] + mf.y * wr[6] + mf.z * wr[10] + mf.w * wr[14];
    float a3 = mf.x * wr[3] + mf.y * wr[7] + mf.z * wr[11] + mf.w * wr[15];
    for (int mask = 1; mask < 64; mask <<= 1) {
        a0 += __shfl_xor(a0, mask);
        a1 += __shfl_xor(a1, mask);
        a2 += __shfl_xor(a2, mask);
        a3 += __shfl_xor(a3, mask);
    }
    if (lane == 0) {
        float gl[4] = {a0 + bg[0], a1 + bg[1], a2 + bg[2], a3 + bg[3]};
        float m = fmaxf(fmaxf(gl[0], gl[1]), fmaxf(gl[2], gl[3]));
        float w[4];
        float wsum = 0.f;
        for (int kk = 0; kk < 4; kk++) { w[kk] = expf(gl[kk] - m); wsum += w[kk]; }
        float o0 = 0.f, o1 = 0.f, q0 = 0.f, q1 = 0.f;
        for (int kk = 0; kk < 4; kk++) {
            float l0 = agg2[((size_t)kk * M + n) * 2];
            float l1 = agg2[((size_t)kk * M + n) * 2 + 1];
            float mm = fmaxf(l0, l1);
            float lse = mm + logf(expf(l0 - mm) + expf(l1 - mm));
            float lp0 = l0 - lse, lp1 = l1 - lse;
            float wk = w[kk] / wsum;
            o0 += wk * lp0; o1 += wk * lp1;
            q0 += wk * expf(lp0); q1 += wk * expf(lp1);
        }
        out[(size_t)n * 2] = o0;
        out[(size_t)n * 2 + 1] = o1;
        out[(size_t)2 * M + n * 2] = q0;
        out[(size_t)2 * M + n * 2 + 1] = q1;
    }
}

extern "C" void kernel_launch(void* const* d_in, const int* in_sizes, int n_in,
                              void* d_out, int out_size, void* d_ws, size_t ws_size,
                              hipStream_t stream) {
    const float* flatten = (const float*)d_in[0];
    const float* moe     = (const float*)d_in[1];
    const int*   edge    = (const int*)d_in[2];   // [K][2][E]
    const float* W1      = (const float*)d_in[3]; // [K][256][64]
    const float* b1      = (const float*)d_in[4]; // [K][64]
    const float* gamma   = (const float*)d_in[5];
    const float* beta    = (const float*)d_in[6];
    const float* W2      = (const float*)d_in[7]; // [K][64][2]
    const float* b2      = (const float*)d_in[8]; // [K][2]
    const float* Wg      = (const float*)d_in[9]; // [256][4]
    const float* bg      = (const float*)d_in[10];
    float* out = (float*)d_out;

    const int N = NN, E = EE;
    const int nblk = (N + 255) / 256;

    char* ws = (char*)d_ws;
    size_t off = 0;
    auto alloc = [&](size_t bytes) -> void* {
        void* p = (void*)(ws + off);
        off += (bytes + 255) & ~(size_t)255;
        return p;
    };
    int*   cnt     = (int*)alloc((size_t)N * 4);
    float* dis     = (float*)alloc((size_t)N * 4);
    float* h       = (float*)alloc((size_t)N * 64 * 4);
    float* agg     = (float*)alloc((size_t)N * 64 * 4);
    float* h2      = (float*)alloc((size_t)N * 2 * 4);
    float* agg2    = (float*)alloc((size_t)KEXP * N * 2 * 4);
    float* partial = (float*)alloc((size_t)nblk * 128 * 4);
    float* mu_istd = (float*)alloc(128 * 4);
    (void)ws_size; (void)in_sizes; (void)n_in; (void)out_size;

    for (int k = 0; k < KEXP; k++) {
        const int* src = edge + (size_t)k * 2 * E;
        const int* dstp = src + E;
        hipMemsetAsync(cnt, 0, (size_t)N * 4, stream);
        deg_kernel<<<(E + 255) / 256, 256, 0, stream>>>(dstp, cnt, E);
        dis_kernel<<<(N + 255) / 256, 256, 0, stream>>>(cnt, dis, N);
        gemm1_kernel<<<(N + 63) / 64, 256, 0, stream>>>(
            flatten, W1 + (size_t)k * 256 * 64, b1 + (size_t)k * 64, dis, h, agg, N);
        edge_agg1<<<(int)(((size_t)E * 64 + 255) / 256), 256, 0, stream>>>(
            src, dstp, dis, h, agg, E);
        relu_stats<<<nblk, 256, 0, stream>>>(agg, partial, N);
        stats_fin<<<1, 64, 0, stream>>>(partial, nblk, mu_istd, N);
        bn_gemm2<<<(int)(((size_t)N * 64 + 255) / 256), 256, 0, stream>>>(
            agg, mu_istd, gamma + (size_t)k * 64, beta + (size_t)k * 64,
            W2 + (size_t)k * 128, b2 + (size_t)k * 2, dis, h2,
            agg2 + (size_t)k * N * 2, N);
        edge_agg2<<<(E + 255) / 256, 256, 0, stream>>>(
            src, dstp, dis, h2, agg2 + (size_t)k * N * 2, E);
    }
    final_kernel<<<(int)(((size_t)N * 64 + 255) / 256), 256, 0, stream>>>(
        moe, Wg, bg, agg2, out, N);
}

// Round 2
// 1864.582 us; speedup vs baseline: 1.7962x; 1.7962x over previous
//
#include <hip/hip_runtime.h>
#include <math.h>

#define NN 100000
#define KEXP 4
#define EE 1600000
#define EPSV 1e-5f
#define NBLK 391   // ceil(100000/256)

// ---------------- degree histogram (all experts) ----------------
__global__ __launch_bounds__(256) void deg_kernel(const int* __restrict__ edge,
                                                  int* __restrict__ cnt, int n, int E) {
    int k = blockIdx.y;
    int e = blockIdx.x * 256 + threadIdx.x;
    if (e < E) {
        int d = edge[(size_t)k * 2 * E + E + e];
        atomicAdd(&cnt[(size_t)k * n + d], 1);
    }
}

__global__ __launch_bounds__(256) void dis_kernel(const int* __restrict__ cnt,
                                                  float* __restrict__ dis, int total) {
    int i = blockIdx.x * 256 + threadIdx.x;
    if (i < total) dis[i] = rsqrtf((float)cnt[i] + 2.0f);
}

// ---------------- CSR build: per-block inclusive scan ----------------
__global__ __launch_bounds__(256) void scan_blocks(const int* __restrict__ cnt,
                                                   int* __restrict__ rowptr,
                                                   int* __restrict__ bsum, int n) {
    int k = blockIdx.y;
    int t = threadIdx.x;
    int i = blockIdx.x * 256 + t;
    __shared__ int sd[256];
    int v = (i < n) ? cnt[(size_t)k * n + i] : 0;
    sd[t] = v;
    __syncthreads();
    for (int o = 1; o < 256; o <<= 1) {
        int x = (t >= o) ? sd[t - o] : 0;
        __syncthreads();
        sd[t] += x;
        __syncthreads();
    }
    if (i < n) rowptr[(size_t)k * (n + 1) + i] = sd[t] - v;  // exclusive-within-block
    if (t == 255) bsum[k * gridDim.x + blockIdx.x] = sd[255];
}

__global__ __launch_bounds__(512) void scan_bsum(int* __restrict__ bsum,
                                                 int* __restrict__ rowptr,
                                                 int nblk, int n, int E) {
    int k = blockIdx.x;
    int t = threadIdx.x;
    __shared__ int sd[512];
    int v = (t < nblk) ? bsum[k * nblk + t] : 0;
    sd[t] = v;
    __syncthreads();
    for (int o = 1; o < 512; o <<= 1) {
        int x = (t >= o) ? sd[t - o] : 0;
        __syncthreads();
        sd[t] += x;
        __syncthreads();
    }
    if (t < nblk) bsum[k * nblk + t] = sd[t] - v;  // exclusive block offsets
    if (t == 0) rowptr[(size_t)k * (n + 1) + n] = E;
}

__global__ __launch_bounds__(256) void scan_add(int* __restrict__ rowptr,
                                                const int* __restrict__ bsum,
                                                int* __restrict__ cursor, int n) {
    int k = blockIdx.y;
    int i = blockIdx.x * 256 + threadIdx.x;
    if (i < n) {
        int off = bsum[k * gridDim.x + blockIdx.x];
        size_t idx = (size_t)k * (n + 1) + i;
        int val = rowptr[idx] + off;
        rowptr[idx] = val;
        cursor[(size_t)k * n + i] = val;
    }
}

__global__ __launch_bounds__(256) void scatter_kernel(const int* __restrict__ edge,
                                                      int* __restrict__ cursor,
                                                      int* __restrict__ adj, int n, int E) {
    int k = blockIdx.y;
    int e = blockIdx.x * 256 + threadIdx.x;
    if (e < E) {
        const int* base = edge + (size_t)k * 2 * E;
        int s = base[e];
        int d = base[E + e];
        int pos = atomicAdd(&cursor[(size_t)k * n + d], 1);
        adj[(size_t)k * E + pos] = s;
    }
}

// ---------------- GEMM1: h = A @ W (M x 256 x 64) ----------------
__global__ __launch_bounds__(256) void gemm1_kernel(
    const float* __restrict__ A,    // [M,256]
    const float* __restrict__ W,    // [256,64]
    float* __restrict__ h,          // [M,64]
    int M) {
    __shared__ __align__(16) float As[64][65];
    __shared__ __align__(16) float Ws[64][68];
    int t = threadIdx.x;
    int row0 = blockIdx.x * 64;
    int tr = t >> 4;   // 0..15
    int tc = t & 15;   // 0..15
    float acc[4][4] = {{0.f}};

    for (int kc = 0; kc < 256; kc += 64) {
        for (int i = 0; i < 4; i++) {
            int fid = t + i * 256;
            int r = fid >> 4;
            int c4 = (fid & 15) << 2;
            int row = row0 + r;
            float4 v = make_float4(0.f, 0.f, 0.f, 0.f);
            if (row < M) v = *(const float4*)&A[(size_t)row * 256 + kc + c4];
            As[r][c4] = v.x; As[r][c4 + 1] = v.y; As[r][c4 + 2] = v.z; As[r][c4 + 3] = v.w;
        }
        for (int i = 0; i < 4; i++) {
            int fid = t + i * 256;
            int r = fid >> 4;
            int c4 = (fid & 15) << 2;
            float4 v = *(const float4*)&W[(size_t)(kc + r) * 64 + c4];
            *(float4*)&Ws[r][c4] = v;
        }
        __syncthreads();
        for (int kk = 0; kk < 64; kk++) {
            float a0 = As[tr * 4 + 0][kk];
            float a1 = As[tr * 4 + 1][kk];
            float a2 = As[tr * 4 + 2][kk];
            float a3 = As[tr * 4 + 3][kk];
            float4 w = *(const float4*)&Ws[kk][tc * 4];
            acc[0][0] += a0 * w.x; acc[0][1] += a0 * w.y; acc[0][2] += a0 * w.z; acc[0][3] += a0 * w.w;
            acc[1][0] += a1 * w.x; acc[1][1] += a1 * w.y; acc[1][2] += a1 * w.z; acc[1][3] += a1 * w.w;
            acc[2][0] += a2 * w.x; acc[2][1] += a2 * w.y; acc[2][2] += a2 * w.z; acc[2][3] += a2 * w.w;
            acc[3][0] += a3 * w.x; acc[3][1] += a3 * w.y; acc[3][2] += a3 * w.z; acc[3][3] += a3 * w.w;
        }
        __syncthreads();
    }
    for (int i = 0; i < 4; i++) {
        int row = row0 + tr * 4 + i;
        if (row >= M) continue;
        float4 v = make_float4(acc[i][0], acc[i][1], acc[i][2], acc[i][3]);
        *(float4*)&h[(size_t)row * 64 + tc * 4] = v;
    }
}

// ---------------- gather agg1: wave per node, lane = feature; fused relu ----
__global__ __launch_bounds__(256) void gather1(const int* __restrict__ rowptr,
                                               const int* __restrict__ adj,
                                               const float* __restrict__ dis,
                                               const float* __restrict__ h,
                                               const float* __restrict__ b1,
                                               float* __restrict__ x, int n) {
    int node = blockIdx.x * 4 + (threadIdx.x >> 6);
    int lane = threadIdx.x & 63;
    if (node >= n) return;
    int beg = rowptr[node], end = rowptr[node + 1];
    float acc = 0.f;
    int j = beg;
    for (; j + 2 <= end; j += 2) {
        int s0 = adj[j], s1 = adj[j + 1];
        float d0 = dis[s0], d1 = dis[s1];
        float v0 = h[(size_t)s0 * 64 + lane];
        float v1 = h[(size_t)s1 * 64 + lane];
        acc += d0 * v0;
        acc += d1 * v1;
    }
    if (j < end) {
        int s0 = adj[j];
        acc += dis[s0] * h[(size_t)s0 * 64 + lane];
    }
    float dn = dis[node];
    float val = dn * acc + 2.f * dn * dn * h[(size_t)node * 64 + lane] + b1[lane];
    x[(size_t)node * 64 + lane] = fmaxf(val, 0.f);
}

// ---------------- BN column stats: grid-stride + atomic finalize ----------
__global__ __launch_bounds__(256) void stats_kernel(const float* __restrict__ x,
                                                    float* __restrict__ accum, int n) {
    int c = threadIdx.x & 63;
    int w = threadIdx.x >> 6;
    float s = 0.f, q = 0.f;
    for (int r = blockIdx.x * 4 + w; r < n; r += gridDim.x * 4) {
        float v = x[(size_t)r * 64 + c];
        s += v; q += v * v;
    }
    __shared__ float ls[4][64];
    __shared__ float lq[4][64];
    ls[w][c] = s; lq[w][c] = q;
    __syncthreads();
    if (threadIdx.x < 64) {
        float S = ls[0][c] + ls[1][c] + ls[2][c] + ls[3][c];
        float Q = lq[0][c] + lq[1][c] + lq[2][c] + lq[3][c];
        unsafeAtomicAdd(&accum[c], S);
        unsafeAtomicAdd(&accum[64 + c], Q);
    }
}

__global__ void stats_fin(const float* __restrict__ accum,
                          float* __restrict__ mu_istd, int M) {
    int c = threadIdx.x;  // 64 threads
    float mu = accum[c] / (float)M;
    float var = accum[64 + c] / (float)M - mu * mu;
    mu_istd[c] = mu;
    mu_istd[64 + c] = rsqrtf(var + EPSV);
}

// ---------------- BN apply + GEMM2 (64 -> 2) ----------------
__global__ __launch_bounds__(256) void bn_gemm2(const float* __restrict__ x,
                                                const float* __restrict__ mu_istd,
                                                const float* __restrict__ g,
                                                const float* __restrict__ bt,
                                                const float* __restrict__ W2,
                                                float* __restrict__ h2, int M) {
    int wid = (int)((blockIdx.x * (size_t)blockDim.x + threadIdx.x) >> 6);
    int c = threadIdx.x & 63;
    if (wid >= M) return;
    float v = x[(size_t)wid * 64 + c];
    v = (v - mu_istd[c]) * mu_istd[64 + c] * g[c] + bt[c];
    float p0 = v * W2[c * 2];
    float p1 = v * W2[c * 2 + 1];
    for (int off = 32; off; off >>= 1) {
        p0 += __shfl_down(p0, off);
        p1 += __shfl_down(p1, off);
    }
    if (c == 0) {
        float2 o = make_float2(p0, p1);
        *(float2*)&h2[(size_t)wid * 2] = o;
    }
}

// ---------------- gather agg2: thread per node ----------------
__global__ __launch_bounds__(256) void gather2(const int* __restrict__ rowptr,
                                               const int* __restrict__ adj,
                                               const float* __restrict__ dis,
                                               const float* __restrict__ h2,
                                               const float* __restrict__ b2,
                                               float* __restrict__ agg2, int n) {
    int node = blockIdx.x * 256 + threadIdx.x;
    if (node >= n) return;
    int beg = rowptr[node], end = rowptr[node + 1];
    float a0 = 0.f, a1 = 0.f;
    int j = beg;
    for (; j + 2 <= end; j += 2) {
        int s0 = adj[j], s1 = adj[j + 1];
        float d0 = dis[s0], d1 = dis[s1];
        float2 v0 = *(const float2*)&h2[(size_t)s0 * 2];
        float2 v1 = *(const float2*)&h2[(size_t)s1 * 2];
        a0 += d0 * v0.x + d1 * v1.x;
        a1 += d0 * v0.y + d1 * v1.y;
    }
    if (j < end) {
        int s0 = adj[j];
        float d0 = dis[s0];
        float2 v0 = *(const float2*)&h2[(size_t)s0 * 2];
        a0 += d0 * v0.x;
        a1 += d0 * v0.y;
    }
    float dn = dis[node];
    float sc = 2.f * dn * dn;
    float2 hv = *(const float2*)&h2[(size_t)node * 2];
    float2 o;
    o.x = dn * a0 + sc * hv.x + b2[0];
    o.y = dn * a1 + sc * hv.y + b2[1];
    *(float2*)&agg2[(size_t)node * 2] = o;
}

// ---------------- gating + mixture output ----------------
__global__ __launch_bounds__(256) void final_kernel(const float* __restrict__ moe,
                                                    const float* __restrict__ Wg,
                                                    const float* __restrict__ bg,
                                                    const float* __restrict__ agg2,  // [K][N][2]
                                                    float* __restrict__ out, int M) {
    int n = (int)((blockIdx.x * (size_t)blockDim.x + threadIdx.x) >> 6);
    int lane = threadIdx.x & 63;
    if (n >= M) return;
    float4 mf = *(const float4*)&moe[(size_t)n * 256 + lane * 4];
    const float* wr = &Wg[lane * 16];
    float a0 = mf.x * wr[0] + mf.y * wr[4] + mf.z * wr[8] + mf.w * wr[12];
    float a1 = mf.x * wr[1] + mf.y * wr[5] + mf.z * wr[9] + mf.w * wr[13];
    float a2 = mf.x * wr[2] + mf.y * wr[6] + mf.z * wr[10] + mf.w * wr[14];
    float a3 = mf.x * wr[3] + mf.y * wr[7] + mf.z * wr[11] + mf.w * wr[15];
    for (int mask = 1; mask < 64; mask <<= 1) {
        a0 += __shfl_xor(a0, mask);
        a1 += __shfl_xor(a1, mask);
        a2 += __shfl_xor(a2, mask);
        a3 += __shfl_xor(a3, mask);
    }
    if (lane == 0) {
        float gl[4] = {a0 + bg[0], a1 + bg[1], a2 + bg[2], a3 + bg[3]};
        float m = fmaxf(fmaxf(gl[0], gl[1]), fmaxf(gl[2], gl[3]));
        float w[4];
        float wsum = 0.f;
        for (int kk = 0; kk < 4; kk++) { w[kk] = expf(gl[kk] - m); wsum += w[kk]; }
        float o0 = 0.f, o1 = 0.f, q0 = 0.f, q1 = 0.f;
        for (int kk = 0; kk < 4; kk++) {
            float l0 = agg2[((size_t)kk * M + n) * 2];
            float l1 = agg2[((size_t)kk * M + n) * 2 + 1];
            float mm = fmaxf(l0, l1);
            float lse = mm + logf(expf(l0 - mm) + expf(l1 - mm));
            float lp0 = l0 - lse, lp1 = l1 - lse;
            float wk = w[kk] / wsum;
            o0 += wk * lp0; o1 += wk * lp1;
            q0 += wk * expf(lp0); q1 += wk * expf(lp1);
        }
        out[(size_t)n * 2] = o0;
        out[(size_t)n * 2 + 1] = o1;
        out[(size_t)2 * M + n * 2] = q0;
        out[(size_t)2 * M + n * 2 + 1] = q1;
    }
}

extern "C" void kernel_launch(void* const* d_in, const int* in_sizes, int n_in,
                              void* d_out, int out_size, void* d_ws, size_t ws_size,
                              hipStream_t stream) {
    const float* flatten = (const float*)d_in[0];
    const float* moe     = (const float*)d_in[1];
    const int*   edge    = (const int*)d_in[2];   // [K][2][E]
    const float* W1      = (const float*)d_in[3]; // [K][256][64]
    const float* b1      = (const float*)d_in[4]; // [K][64]
    const float* gamma   = (const float*)d_in[5];
    const float* beta    = (const float*)d_in[6];
    const float* W2      = (const float*)d_in[7]; // [K][64][2]
    const float* b2      = (const float*)d_in[8]; // [K][2]
    const float* Wg      = (const float*)d_in[9]; // [256][4]
    const float* bg      = (const float*)d_in[10];
    float* out = (float*)d_out;

    const int N = NN, E = EE, K = KEXP;

    char* ws = (char*)d_ws;
    size_t off = 0;
    auto alloc = [&](size_t bytes) -> void* {
        void* p = (void*)(ws + off);
        off += (bytes + 255) & ~(size_t)255;
        return p;
    };
    int*   cnt     = (int*)alloc((size_t)K * N * 4);
    int*   rowptr  = (int*)alloc((size_t)K * (N + 1) * 4);
    int*   cursor  = (int*)alloc((size_t)K * N * 4);
    float* dis     = (float*)alloc((size_t)K * N * 4);
    int*   bsum    = (int*)alloc((size_t)K * NBLK * 4);
    int*   adj     = (int*)alloc((size_t)K * E * 4);
    float* h       = (float*)alloc((size_t)N * 64 * 4);
    float* x       = (float*)alloc((size_t)N * 64 * 4);
    float* h2      = (float*)alloc((size_t)N * 2 * 4);
    float* agg2    = (float*)alloc((size_t)K * N * 2 * 4);
    float* accum   = (float*)alloc((size_t)K * 128 * 4);
    float* mu_istd = (float*)alloc(128 * 4);
    (void)ws_size; (void)in_sizes; (void)n_in; (void)out_size;

    const int egrid = (E + 255) / 256;

    // ---- batched CSR build for all experts ----
    hipMemsetAsync(cnt, 0, (size_t)K * N * 4, stream);
    hipMemsetAsync(accum, 0, (size_t)K * 128 * 4, stream);
    deg_kernel<<<dim3(egrid, K), 256, 0, stream>>>(edge, cnt, N, E);
    dis_kernel<<<(K * N + 255) / 256, 256, 0, stream>>>(cnt, dis, K * N);
    scan_blocks<<<dim3(NBLK, K), 256, 0, stream>>>(cnt, rowptr, bsum, N);
    scan_bsum<<<K, 512, 0, stream>>>(bsum, rowptr, NBLK, N, E);
    scan_add<<<dim3(NBLK, K), 256, 0, stream>>>(rowptr, bsum, cursor, N);
    scatter_kernel<<<dim3(egrid, K), 256, 0, stream>>>(edge, cursor, adj, N, E);

    // ---- per-expert pipeline ----
    for (int k = 0; k < K; k++) {
        const int* rp = rowptr + (size_t)k * (N + 1);
        const int* aj = adj + (size_t)k * E;
        const float* dk = dis + (size_t)k * N;
        gemm1_kernel<<<(N + 63) / 64, 256, 0, stream>>>(
            flatten, W1 + (size_t)k * 256 * 64, h, N);
        gather1<<<(N + 3) / 4, 256, 0, stream>>>(
            rp, aj, dk, h, b1 + (size_t)k * 64, x, N);
        stats_kernel<<<400, 256, 0, stream>>>(x, accum + (size_t)k * 128, N);
        stats_fin<<<1, 64, 0, stream>>>(accum + (size_t)k * 128, mu_istd, N);
        bn_gemm2<<<(int)(((size_t)N * 64 + 255) / 256), 256, 0, stream>>>(
            x, mu_istd, gamma + (size_t)k * 64, beta + (size_t)k * 64,
            W2 + (size_t)k * 128, h2, N);
        gather2<<<(N + 255) / 256, 256, 0, stream>>>(
            rp, aj, dk, h2, b2 + (size_t)k * 2, agg2 + (size_t)k * N * 2, N);
    }
    final_kernel<<<(int)(((size_t)N * 64 + 255) / 256), 256, 0, stream>>>(
        moe, Wg, bg, agg2, out, N);
}